// Round 1
// baseline (1554.293 us; speedup 1.0000x reference)
//
#include <hip/hip_runtime.h>

#define NPIX 4096
#define CIN  256
#define DK   32

// out[b, r0+i, n] = bias[r0+i] + sum_c w[r0+i, c] * x[b, c, n]
// grid (NPIX/256, R/32, B), block 256. Thread t handles pixel n0+t, 32 rows.
__global__ void proj_kernel(const float* __restrict__ x, const float* __restrict__ w,
                            const float* __restrict__ bias, float* __restrict__ out) {
    __shared__ float xs[32][256];
    const int t  = threadIdx.x;
    const int n0 = blockIdx.x * 256;
    const int r0 = blockIdx.y * 32;
    const int b  = blockIdx.z;
    const int Rtot = gridDim.y * 32;
    float acc[32];
#pragma unroll
    for (int i = 0; i < 32; ++i) acc[i] = bias[r0 + i];
    for (int cc = 0; cc < CIN; cc += 32) {
        __syncthreads();
#pragma unroll
        for (int r = 0; r < 32; ++r)
            xs[r][t] = x[(size_t)(b * CIN + cc + r) * NPIX + n0 + t];
        __syncthreads();
        float xr[32];
#pragma unroll
        for (int c = 0; c < 32; ++c) xr[c] = xs[c][t];
#pragma unroll
        for (int i = 0; i < 32; ++i) {
            const float* wrow = w + (r0 + i) * CIN + cc;  // uniform -> s_load
#pragma unroll
            for (int c = 0; c < 32; ++c) acc[i] = fmaf(wrow[c], xr[c], acc[i]);
        }
    }
#pragma unroll
    for (int i = 0; i < 32; ++i)
        out[(size_t)(b * Rtot + r0 + i) * NPIX + n0 + t] = acc[i];
}

// Pass 1 of softmax: row max m_i and 1/sum_j exp(e_ij - m_i).
// grid (NPIX/64, B), block 256. i-tile 64, j-tile 128; thread = 4i x 8j.
__global__ void stats_kernel(const float* __restrict__ qT, const float* __restrict__ kT,
                             float* __restrict__ mo, float* __restrict__ rlo) {
    __shared__ float qs[32][64];
    __shared__ float ks[32][128];
    __shared__ float red_m[16][64];
    __shared__ float red_s[16][64];
    const int t  = threadIdx.x;
    const int i0 = blockIdx.x * 64;
    const int b  = blockIdx.y;
    for (int idx = t; idx < 32 * 64; idx += 256) {
        int d = idx >> 6, il = idx & 63;
        qs[d][il] = qT[(size_t)(b * DK + d) * NPIX + i0 + il];
    }
    const int ti = t & 15;   // 16 groups * 4 i
    const int tj = t >> 4;   // 16 groups * 8 j
    float m[4], ssum[4];
#pragma unroll
    for (int r = 0; r < 4; ++r) { m[r] = -1e30f; ssum[r] = 0.f; }
    for (int jt = 0; jt < NPIX; jt += 128) {
        __syncthreads();
        for (int idx = t; idx < 32 * 128; idx += 256) {
            int d = idx >> 7, jl = idx & 127;
            ks[d][jl] = kT[(size_t)(b * DK + d) * NPIX + jt + jl];
        }
        __syncthreads();
        float e[4][8];
#pragma unroll
        for (int r = 0; r < 4; ++r)
#pragma unroll
            for (int s = 0; s < 8; ++s) e[r][s] = 0.f;
#pragma unroll 8
        for (int d = 0; d < 32; ++d) {
            float4 q4 = *reinterpret_cast<const float4*>(&qs[d][4 * ti]);
            float4 ka = *reinterpret_cast<const float4*>(&ks[d][8 * tj]);
            float4 kb = *reinterpret_cast<const float4*>(&ks[d][8 * tj + 4]);
            float qv[4] = {q4.x, q4.y, q4.z, q4.w};
            float kv[8] = {ka.x, ka.y, ka.z, ka.w, kb.x, kb.y, kb.z, kb.w};
#pragma unroll
            for (int r = 0; r < 4; ++r)
#pragma unroll
                for (int s = 0; s < 8; ++s) e[r][s] = fmaf(qv[r], kv[s], e[r][s]);
        }
#pragma unroll
        for (int r = 0; r < 4; ++r) {
            float lm = e[r][0];
#pragma unroll
            for (int s = 1; s < 8; ++s) lm = fmaxf(lm, e[r][s]);
            float mn = fmaxf(m[r], lm);
            float add = 0.f;
#pragma unroll
            for (int s = 0; s < 8; ++s) add += __expf(e[r][s] - mn);
            ssum[r] = ssum[r] * __expf(m[r] - mn) + add;
            m[r] = mn;
        }
    }
    __syncthreads();
#pragma unroll
    for (int r = 0; r < 4; ++r) { red_m[tj][4 * ti + r] = m[r]; red_s[tj][4 * ti + r] = ssum[r]; }
    __syncthreads();
    if (t < 64) {
        float M = -1e30f;
#pragma unroll
        for (int g = 0; g < 16; ++g) M = fmaxf(M, red_m[g][t]);
        float L = 0.f;
#pragma unroll
        for (int g = 0; g < 16; ++g) L += red_s[g][t] * __expf(red_m[g][t] - M);
        mo[b * NPIX + i0 + t]  = M;
        rlo[b * NPIX + i0 + t] = 1.0f / L;
    }
}

// Fused pass 2: out[b,c,i] = gamma * sum_j V[c,j] * exp(e_ij - m_i)/l_i + x[b,c,i]
// grid (NPIX/128, CIN/128, B), block 256. Block tile 128c x 128i, j-step 32.
__global__ void attnv_kernel(const float* __restrict__ qT, const float* __restrict__ kT,
                             const float* __restrict__ v,  const float* __restrict__ mo,
                             const float* __restrict__ rlo, const float* __restrict__ xin,
                             const float* __restrict__ gamma, float* __restrict__ out) {
    __shared__ float qs[32][128];   // 16 KB, persistent
    __shared__ float ks[32][32];    // 4 KB, per j-tile
    __shared__ float Ss[32][132];   // 16.5 KB; pad 132 (mult of 4) keeps float4 align
    __shared__ float Vs[128][33];   // 16.9 KB; pad 33 breaks bank aliasing
    __shared__ float ms[128];
    __shared__ float rls[128];
    const int t  = threadIdx.x;
    const int i0 = blockIdx.x * 128;
    const int c0 = blockIdx.y * 128;
    const int b  = blockIdx.z;

    for (int idx = t; idx < 32 * 128; idx += 256) {
        int d = idx >> 7, il = idx & 127;
        qs[d][il] = qT[(size_t)(b * DK + d) * NPIX + i0 + il];
    }
    if (t < 128) { ms[t] = mo[b * NPIX + i0 + t]; rls[t] = rlo[b * NPIX + i0 + t]; }

    float acc[8][8];
#pragma unroll
    for (int r = 0; r < 8; ++r)
#pragma unroll
        for (int s = 0; s < 8; ++s) acc[r][s] = 0.f;

    const int ti   = t & 31;        // phase1: 32 groups * 4 i
    const int tjj  = t >> 5;        // phase1: 8 groups * 4 j
    const int ti2  = t & 15;        // phase2: 16 groups * 8 i
    const int tc   = t >> 4;        // phase2: 16 groups * 8 c
    const int kd   = t >> 3;        // ks staging
    const int kcol = (t & 7) * 4;
    const int vc   = t >> 1;        // Vs staging
    const int voff = (t & 1) * 16;

    for (int jt = 0; jt < NPIX; jt += 32) {
        __syncthreads();
        {
            float4 kv = *reinterpret_cast<const float4*>(&kT[(size_t)(b * DK + kd) * NPIX + jt + kcol]);
            *reinterpret_cast<float4*>(&ks[kd][kcol]) = kv;
        }
#pragma unroll
        for (int u = 0; u < 2; ++u) {
            float4 va = *reinterpret_cast<const float4*>(&v[(size_t)(b * CIN + c0 + vc) * NPIX + jt + voff + 8 * u]);
            float4 vb = *reinterpret_cast<const float4*>(&v[(size_t)(b * CIN + c0 + vc) * NPIX + jt + voff + 8 * u + 4]);
            Vs[vc][voff + 8 * u + 0] = va.x; Vs[vc][voff + 8 * u + 1] = va.y;
            Vs[vc][voff + 8 * u + 2] = va.z; Vs[vc][voff + 8 * u + 3] = va.w;
            Vs[vc][voff + 8 * u + 4] = vb.x; Vs[vc][voff + 8 * u + 5] = vb.y;
            Vs[vc][voff + 8 * u + 6] = vb.z; Vs[vc][voff + 8 * u + 7] = vb.w;
        }
        __syncthreads();

        // phase 1: E = Q^T K tile (fp32), exp -> Ss[j][i]
        float e[4][4];
#pragma unroll
        for (int r = 0; r < 4; ++r)
#pragma unroll
            for (int s = 0; s < 4; ++s) e[r][s] = 0.f;
#pragma unroll 8
        for (int d = 0; d < 32; ++d) {
            float4 q4 = *reinterpret_cast<const float4*>(&qs[d][4 * ti]);
            float4 k4 = *reinterpret_cast<const float4*>(&ks[d][4 * tjj]);
            float qv[4] = {q4.x, q4.y, q4.z, q4.w};
            float kv[4] = {k4.x, k4.y, k4.z, k4.w};
#pragma unroll
            for (int r = 0; r < 4; ++r)
#pragma unroll
                for (int s = 0; s < 4; ++s) e[r][s] = fmaf(qv[r], kv[s], e[r][s]);
        }
        float mi[4], ri[4];
#pragma unroll
        for (int r = 0; r < 4; ++r) { mi[r] = ms[4 * ti + r]; ri[r] = rls[4 * ti + r]; }
#pragma unroll
        for (int s = 0; s < 4; ++s) {
            float4 p;
            p.x = __expf(e[0][s] - mi[0]) * ri[0];
            p.y = __expf(e[1][s] - mi[1]) * ri[1];
            p.z = __expf(e[2][s] - mi[2]) * ri[2];
            p.w = __expf(e[3][s] - mi[3]) * ri[3];
            *reinterpret_cast<float4*>(&Ss[4 * tjj + s][4 * ti]) = p;
        }
        __syncthreads();

        // phase 2: acc[c][i] += V[c,j] * S[j,i]   (8x8 per thread)
#pragma unroll 8
        for (int j = 0; j < 32; ++j) {
            float4 sa = *reinterpret_cast<const float4*>(&Ss[j][8 * ti2]);
            float4 sb = *reinterpret_cast<const float4*>(&Ss[j][8 * ti2 + 4]);
            float sv[8] = {sa.x, sa.y, sa.z, sa.w, sb.x, sb.y, sb.z, sb.w};
#pragma unroll
            for (int r = 0; r < 8; ++r) {
                float vvv = Vs[8 * tc + r][j];   // 4 distinct addrs/wave -> broadcast
#pragma unroll
                for (int s = 0; s < 8; ++s) acc[r][s] = fmaf(vvv, sv[s], acc[r][s]);
            }
        }
    }

    const float g = gamma[0];
#pragma unroll
    for (int r = 0; r < 8; ++r) {
        size_t base = (size_t)(b * CIN + c0 + 8 * tc + r) * NPIX + i0 + 8 * ti2;
        float4 x0 = *reinterpret_cast<const float4*>(&xin[base]);
        float4 x1 = *reinterpret_cast<const float4*>(&xin[base + 4]);
        float4 o0, o1;
        o0.x = g * acc[r][0] + x0.x; o0.y = g * acc[r][1] + x0.y;
        o0.z = g * acc[r][2] + x0.z; o0.w = g * acc[r][3] + x0.w;
        o1.x = g * acc[r][4] + x1.x; o1.y = g * acc[r][5] + x1.y;
        o1.z = g * acc[r][6] + x1.z; o1.w = g * acc[r][7] + x1.w;
        *reinterpret_cast<float4*>(&out[base])     = o0;
        *reinterpret_cast<float4*>(&out[base + 4]) = o1;
    }
}

extern "C" void kernel_launch(void* const* d_in, const int* in_sizes, int n_in,
                              void* d_out, int out_size, void* d_ws, size_t ws_size,
                              hipStream_t stream) {
    const float* x     = (const float*)d_in[0];
    const float* wq    = (const float*)d_in[1];
    const float* bq    = (const float*)d_in[2];
    const float* wk    = (const float*)d_in[3];
    const float* bk    = (const float*)d_in[4];
    const float* wv    = (const float*)d_in[5];
    const float* bv    = (const float*)d_in[6];
    const float* gamma = (const float*)d_in[7];
    float* out = (float*)d_out;

    float* ws = (float*)d_ws;
    float* qT = ws;                                  // 4*32*4096   = 0.5M floats
    float* kT = qT + (size_t)4 * DK * NPIX;          // 0.5M floats
    float* vv = kT + (size_t)4 * DK * NPIX;          // 4*256*4096  = 4M floats
    float* mo = vv + (size_t)4 * CIN * NPIX;         // 16K floats
    float* rl = mo + (size_t)4 * NPIX;               // 16K floats
    // total ~20.1 MB of d_ws

    proj_kernel<<<dim3(16, 1, 4), 256, 0, stream>>>(x, wq, bq, qT);
    proj_kernel<<<dim3(16, 1, 4), 256, 0, stream>>>(x, wk, bk, kT);
    proj_kernel<<<dim3(16, 8, 4), 256, 0, stream>>>(x, wv, bv, vv);
    stats_kernel<<<dim3(64, 4), 256, 0, stream>>>(qT, kT, mo, rl);
    attnv_kernel<<<dim3(32, 2, 4), 256, 0, stream>>>(qT, kT, vv, mo, rl, x, gamma, out);
}

// Round 2
// 415.269 us; speedup vs baseline: 3.7429x; 3.7429x over previous
//
#include <hip/hip_runtime.h>

#define NPIX 4096
#define CIN  256
#define DK   32

typedef __attribute__((ext_vector_type(8))) short short8;   // 8 bf16 = 4 VGPR (MFMA A/B frag)
typedef __attribute__((ext_vector_type(4))) float f32x4;    // MFMA C/D frag

__device__ __forceinline__ unsigned short f2bf(float f) {
    unsigned int u = __float_as_uint(f);
    unsigned int r = (u + 0x7fffu + ((u >> 16) & 1u)) >> 16;   // RNE
    return (unsigned short)r;
}

// q/k projection: out[b][n][d] (row-major, d contiguous) bf16.
// y[n][d] = bias[d] + sum_c w[d][c] x[b][c][n].  grid (NPIX/64, B), block 256.
__global__ void proj_qk(const float* __restrict__ x, const float* __restrict__ w,
                        const float* __restrict__ bias, unsigned short* __restrict__ out) {
    __shared__ float xs[32][64];
    const int t = threadIdx.x;
    const int p = t & 63;        // pixel within tile
    const int g = t >> 6;        // wave index = d-group (d = g*8 + r)
    const int n0 = blockIdx.x * 64;
    const int b  = blockIdx.y;
    float acc[8];
#pragma unroll
    for (int r = 0; r < 8; ++r) acc[r] = bias[g * 8 + r];
    for (int cc = 0; cc < CIN; cc += 32) {
        __syncthreads();
        {   // stage 32c x 64p as float4 (512 units, 2/thread)
            int id = t;              // unit 0
            int c = id >> 4, p4 = (id & 15) * 4;
            *reinterpret_cast<float4*>(&xs[c][p4]) =
                *reinterpret_cast<const float4*>(&x[(size_t)(b * CIN + cc + c) * NPIX + n0 + p4]);
            id = t + 256;
            c = id >> 4; p4 = (id & 15) * 4;
            *reinterpret_cast<float4*>(&xs[c][p4]) =
                *reinterpret_cast<const float4*>(&x[(size_t)(b * CIN + cc + c) * NPIX + n0 + p4]);
        }
        __syncthreads();
#pragma unroll
        for (int c = 0; c < 32; ++c) {
            float xv = xs[c][p];
#pragma unroll
            for (int r = 0; r < 8; ++r)
                acc[r] = fmaf(w[(g * 8 + r) * CIN + cc + c], xv, acc[r]);  // uniform -> s_load
        }
    }
    short8 sv;
#pragma unroll
    for (int r = 0; r < 8; ++r) sv[r] = (short)f2bf(acc[r]);
    *reinterpret_cast<short8*>(&out[(size_t)(b * NPIX + n0 + p) * DK + g * 8]) = sv;
}

// v projection: out[b][c][n] bf16.  grid (NPIX/256, CIN/32, B), block 256.
__global__ void proj_v(const float* __restrict__ x, const float* __restrict__ w,
                       const float* __restrict__ bias, unsigned short* __restrict__ out) {
    __shared__ float xs[32][256];
    const int t  = threadIdx.x;
    const int n0 = blockIdx.x * 256;
    const int c0 = blockIdx.y * 32;
    const int b  = blockIdx.z;
    float acc[32];
#pragma unroll
    for (int i = 0; i < 32; ++i) acc[i] = bias[c0 + i];
    for (int cc = 0; cc < CIN; cc += 32) {
        __syncthreads();
#pragma unroll
        for (int u = 0; u < 8; ++u) {   // 2048 float4 units / 256 threads
            int id = t + u * 256;
            int c = id >> 6, p4 = (id & 63) * 4;
            *reinterpret_cast<float4*>(&xs[c][p4]) =
                *reinterpret_cast<const float4*>(&x[(size_t)(b * CIN + cc + c) * NPIX + n0 + p4]);
        }
        __syncthreads();
        float xr[32];
#pragma unroll
        for (int c = 0; c < 32; ++c) xr[c] = xs[c][t];
#pragma unroll
        for (int i = 0; i < 32; ++i) {
            const float* wrow = w + (c0 + i) * CIN + cc;
#pragma unroll
            for (int c = 0; c < 32; ++c) acc[i] = fmaf(wrow[c], xr[c], acc[i]);
        }
    }
#pragma unroll
    for (int i = 0; i < 32; ++i)
        out[(size_t)(b * CIN + c0 + i) * NPIX + n0 + t] = f2bf(acc[i]);
}

// softmax denominators (no max subtraction; |e|<~40 is safe in fp32/bf16 range):
// rl[b][i] = 1 / sum_j exp(e_ij), E via bf16 MFMA.  grid (NPIX/64, B), block 256.
__global__ void stats_kernel(const unsigned short* __restrict__ qR,
                             const unsigned short* __restrict__ kR,
                             float* __restrict__ rl) {
    const int t    = threadIdx.x;
    const int lane = t & 63;
    const int w    = t >> 6;
    const int li   = lane & 15;
    const int quad = lane >> 4;
    const int i0   = blockIdx.x * 64 + w * 16;
    const int b    = blockIdx.y;

    short8 aq = *reinterpret_cast<const short8*>(&qR[(size_t)(b * NPIX + i0 + li) * DK + quad * 8]);
    float s[4] = {0.f, 0.f, 0.f, 0.f};
    const f32x4 zero = {0.f, 0.f, 0.f, 0.f};

    for (int jt = 0; jt < NPIX; jt += 64) {
        short8 b0 = *reinterpret_cast<const short8*>(&kR[(size_t)(b * NPIX + jt +      li) * DK + quad * 8]);
        short8 b1 = *reinterpret_cast<const short8*>(&kR[(size_t)(b * NPIX + jt + 16 + li) * DK + quad * 8]);
        short8 b2 = *reinterpret_cast<const short8*>(&kR[(size_t)(b * NPIX + jt + 32 + li) * DK + quad * 8]);
        short8 b3 = *reinterpret_cast<const short8*>(&kR[(size_t)(b * NPIX + jt + 48 + li) * DK + quad * 8]);
        f32x4 e0 = __builtin_amdgcn_mfma_f32_16x16x32_bf16(aq, b0, zero, 0, 0, 0);
        f32x4 e1 = __builtin_amdgcn_mfma_f32_16x16x32_bf16(aq, b1, zero, 0, 0, 0);
        f32x4 e2 = __builtin_amdgcn_mfma_f32_16x16x32_bf16(aq, b2, zero, 0, 0, 0);
        f32x4 e3 = __builtin_amdgcn_mfma_f32_16x16x32_bf16(aq, b3, zero, 0, 0, 0);
#pragma unroll
        for (int r = 0; r < 4; ++r)
            s[r] += __expf(e0[r]) + __expf(e1[r]) + __expf(e2[r]) + __expf(e3[r]);
    }
    // reduce across the 16 lanes of each quad-row group
#pragma unroll
    for (int off = 1; off < 16; off <<= 1)
#pragma unroll
        for (int r = 0; r < 4; ++r) s[r] += __shfl_xor(s[r], off, 16);
    if (li == 0) {
#pragma unroll
        for (int r = 0; r < 4; ++r)
            rl[b * NPIX + i0 + quad * 4 + r] = 1.0f / s[r];
    }
}

// Fused attention * V:
// out[b][c][i] = gamma * rl_i * sum_j exp(e_ij) * V[c][j] + x[b][c][i]
// grid (NPIX/64, B), block 256 (4 waves; wave w: 16 i x full 256 c). j-step 32.
__global__ __launch_bounds__(256) void attnv_kernel(
        const unsigned short* __restrict__ qR, const unsigned short* __restrict__ kR,
        const unsigned short* __restrict__ vR, const float* __restrict__ rl,
        const float* __restrict__ xin, const float* __restrict__ gamma,
        float* __restrict__ out) {
    __shared__ unsigned short Vs[2][CIN * 40];   // V tile [c][j], row stride 40 bf16 (80B, 16B-aligned)
    __shared__ unsigned short Ps[4][16 * 40];    // per-wave P tile [i][j], stride 40

    const int t    = threadIdx.x;
    const int lane = t & 63;
    const int w    = t >> 6;
    const int li   = lane & 15;
    const int quad = lane >> 4;
    const int i0   = blockIdx.x * 64;
    const int b    = blockIdx.y;
    const int iw   = i0 + w * 16;

    // persistent Q A-frag and rl for this wave's 16 rows
    short8 aq = *reinterpret_cast<const short8*>(&qR[(size_t)(b * NPIX + iw + li) * DK + quad * 8]);
    float rlr[4];
#pragma unroll
    for (int r = 0; r < 4; ++r) rlr[r] = rl[b * NPIX + iw + quad * 4 + r];

    f32x4 acc[16];
#pragma unroll
    for (int nt = 0; nt < 16; ++nt) acc[nt] = (f32x4){0.f, 0.f, 0.f, 0.f};
    const f32x4 zero = {0.f, 0.f, 0.f, 0.f};

    // prologue: stage V tile for jt=0 (thread t stages c-row t: 32 j = 64 B)
    {
        const unsigned short* src = &vR[(size_t)(b * CIN + t) * NPIX + 0];
        uint4 d0 = *reinterpret_cast<const uint4*>(src + 0);
        uint4 d1 = *reinterpret_cast<const uint4*>(src + 8);
        uint4 d2 = *reinterpret_cast<const uint4*>(src + 16);
        uint4 d3 = *reinterpret_cast<const uint4*>(src + 24);
        unsigned short* dst = &Vs[0][t * 40];
        reinterpret_cast<uint4*>(dst)[0] = d0;
        reinterpret_cast<uint4*>(dst)[1] = d1;
        reinterpret_cast<uint4*>(dst)[2] = d2;
        reinterpret_cast<uint4*>(dst)[3] = d3;
    }
    __syncthreads();

    for (int s = 0; s < NPIX / 32; ++s) {
        const int jt  = s * 32;
        const int cur = s & 1;

        // prefetch next V tile into registers
        uint4 n0, n1, n2, n3;
        if (s + 1 < NPIX / 32) {
            const unsigned short* src = &vR[(size_t)(b * CIN + t) * NPIX + jt + 32];
            n0 = *reinterpret_cast<const uint4*>(src + 0);
            n1 = *reinterpret_cast<const uint4*>(src + 8);
            n2 = *reinterpret_cast<const uint4*>(src + 16);
            n3 = *reinterpret_cast<const uint4*>(src + 24);
        }

        // E = Q K^T tile (16i x 32j), K frags direct from global (L1-shared across waves)
        short8 kb0 = *reinterpret_cast<const short8*>(&kR[(size_t)(b * NPIX + jt +      li) * DK + quad * 8]);
        short8 kb1 = *reinterpret_cast<const short8*>(&kR[(size_t)(b * NPIX + jt + 16 + li) * DK + quad * 8]);
        f32x4 e0 = __builtin_amdgcn_mfma_f32_16x16x32_bf16(aq, kb0, zero, 0, 0, 0);
        f32x4 e1 = __builtin_amdgcn_mfma_f32_16x16x32_bf16(aq, kb1, zero, 0, 0, 0);

        // P = exp(E) (unnormalized), write to wave-private LDS in [i][j] layout
#pragma unroll
        for (int r = 0; r < 4; ++r) {
            Ps[w][(quad * 4 + r) * 40 + li]      = f2bf(__expf(e0[r]));
            Ps[w][(quad * 4 + r) * 40 + 16 + li] = f2bf(__expf(e1[r]));
        }
        // re-read as A-operand frag (wave-private: no barrier, compiler inserts lgkmcnt)
        short8 a2 = *reinterpret_cast<const short8*>(&Ps[w][li * 40 + quad * 8]);

        // PV: acc[i][c] += P[i][j] * V[c][j] over all 256 c
#pragma unroll
        for (int nt = 0; nt < 16; ++nt) {
            short8 vf = *reinterpret_cast<const short8*>(&Vs[cur][(nt * 16 + li) * 40 + quad * 8]);
            acc[nt] = __builtin_amdgcn_mfma_f32_16x16x32_bf16(a2, vf, acc[nt], 0, 0, 0);
        }

        // commit prefetched V tile to the other buffer
        if (s + 1 < NPIX / 32) {
            unsigned short* dst = &Vs[cur ^ 1][t * 40];
            reinterpret_cast<uint4*>(dst)[0] = n0;
            reinterpret_cast<uint4*>(dst)[1] = n1;
            reinterpret_cast<uint4*>(dst)[2] = n2;
            reinterpret_cast<uint4*>(dst)[3] = n3;
        }
        __syncthreads();
    }

    // epilogue: out[b][c][i] = g * acc * rl_i + x
    const float g = gamma[0];
#pragma unroll
    for (int nt = 0; nt < 16; ++nt) {
        const int c = nt * 16 + li;
        const size_t base = (size_t)(b * CIN + c) * NPIX + iw + quad * 4;
        float4 xv = *reinterpret_cast<const float4*>(&xin[base]);
        float4 o;
        o.x = g * acc[nt][0] * rlr[0] + xv.x;
        o.y = g * acc[nt][1] * rlr[1] + xv.y;
        o.z = g * acc[nt][2] * rlr[2] + xv.z;
        o.w = g * acc[nt][3] * rlr[3] + xv.w;
        *reinterpret_cast<float4*>(&out[base]) = o;
    }
}

extern "C" void kernel_launch(void* const* d_in, const int* in_sizes, int n_in,
                              void* d_out, int out_size, void* d_ws, size_t ws_size,
                              hipStream_t stream) {
    const float* x     = (const float*)d_in[0];
    const float* wq    = (const float*)d_in[1];
    const float* bq    = (const float*)d_in[2];
    const float* wk    = (const float*)d_in[3];
    const float* bk    = (const float*)d_in[4];
    const float* wv    = (const float*)d_in[5];
    const float* bv    = (const float*)d_in[6];
    const float* gamma = (const float*)d_in[7];
    float* out = (float*)d_out;

    unsigned short* qR = (unsigned short*)d_ws;                  // [B][N][32] bf16, 1 MB
    unsigned short* kR = qR + (size_t)4 * NPIX * DK;             // 1 MB
    unsigned short* vR = kR + (size_t)4 * NPIX * DK;             // [B][C][N] bf16, 8 MB
    float*          rl = (float*)(vR + (size_t)4 * CIN * NPIX);  // [B][N] fp32, 64 KB

    proj_qk<<<dim3(64, 4), 256, 0, stream>>>(x, wq, bq, qR);
    proj_qk<<<dim3(64, 4), 256, 0, stream>>>(x, wk, bk, kR);
    proj_v <<<dim3(16, 8, 4), 256, 0, stream>>>(x, wv, bv, vR);
    stats_kernel<<<dim3(64, 4), 256, 0, stream>>>(qR, kR, rl);
    attnv_kernel<<<dim3(64, 4), 256, 0, stream>>>(qR, kR, vR, rl, x, gamma, out);
}